// Round 1
// 1504.218 us; speedup vs baseline: 1.2599x; 1.2599x over previous
//
#include <hip/hip_runtime.h>
#include <math.h>

#define T_TOTAL 32000
#define BATCH 4
#define TT 64

typedef __bf16 bf16x8 __attribute__((ext_vector_type(8)));
typedef float f32x4 __attribute__((ext_vector_type(4)));
typedef unsigned int uint4v __attribute__((ext_vector_type(4)));
typedef unsigned int uint2v __attribute__((ext_vector_type(2)));

__device__ __forceinline__ unsigned short f2b(float f) {
    unsigned int u = __float_as_uint(f);
    u += 0x7FFFu + ((u >> 16) & 1u);
    return (unsigned short)(u >> 16);
}
__device__ __forceinline__ unsigned int f2b2(float lo, float hi) {
    return (unsigned int)f2b(lo) | ((unsigned int)f2b(hi) << 16);
}
__device__ __forceinline__ bf16x8 ld_bf8(const unsigned short* p) {
    return __builtin_bit_cast(bf16x8, *(const uint4v*)p);
}
__device__ __forceinline__ float fast_sigmoid(float x) {
    return __builtin_amdgcn_rcpf(1.0f + __expf(-x));
}
__device__ __forceinline__ float fast_tanh(float x) {
    return 1.0f - 2.0f * __builtin_amdgcn_rcpf(1.0f + __expf(2.0f * x));
}

// ---------------- weight packing (fp32 -> bf16, fused/padded layouts) ----------
// wgp[l][o(128)][k(224)]: k 0..63 = conv_w[..][k][0] (tap t-d), 64..127 = tap t,
//                         128..207 = cond_w, 208..223 = 0
// wzp[l][r(128)][k(64)]:  r 0..63 = skip_w rows, 64..127 = out_w rows
__global__ void k_pack(const float* __restrict__ conv_w, const float* __restrict__ cond_w,
                       const float* __restrict__ skip_w, const float* __restrict__ out_w,
                       const float* __restrict__ first_w, const float* __restrict__ last1_w,
                       const float* __restrict__ last2_w,
                       unsigned short* __restrict__ wgp, unsigned short* __restrict__ wzp,
                       unsigned short* __restrict__ fwp, unsigned short* __restrict__ l1p,
                       unsigned short* __restrict__ l2p) {
    int i = blockIdx.x * blockDim.x + threadIdx.x;
    if (i < 860160) {  // wgp: 30*128*224
        int l = i / 28672, r = i % 28672;
        int o = r / 224, k = r % 224;
        float v;
        if (k < 64)       v = conv_w[(((size_t)l * 128 + o) * 64 + k) * 2 + 0];
        else if (k < 128) v = conv_w[(((size_t)l * 128 + o) * 64 + (k - 64)) * 2 + 1];
        else if (k < 208) v = cond_w[((size_t)l * 128 + o) * 80 + (k - 128)];
        else              v = 0.0f;
        wgp[i] = f2b(v);
        return;
    }
    i -= 860160;
    if (i < 245760) {  // wzp: 30*128*64
        int l = i / 8192, rr = (i % 8192) / 64, k = i % 64;
        float v = (rr < 64) ? skip_w[((size_t)l * 64 + rr) * 64 + k]
                            : out_w[((size_t)l * 64 + (rr - 64)) * 64 + k];
        wzp[i] = f2b(v);
        return;
    }
    i -= 245760;
    if (i < 16384) { fwp[i] = f2b(first_w[i]); return; }   // 64*256
    i -= 16384;
    if (i < 4096) { l1p[i] = f2b(last1_w[i]); return; }    // 64*64
    i -= 4096;
    if (i < 16384) { l2p[i] = f2b(last2_w[i]); return; }   // 256*64
}

// ---------------- upsample network ----------------
__global__ void k_convin(const float* __restrict__ c, const float* __restrict__ w,
                         float* __restrict__ c1) {
    int idx = blockIdx.x * blockDim.x + threadIdx.x;
    if (idx >= BATCH * 80 * 400) return;
    int f = idx % 400;
    int o = (idx / 400) % 80;
    int b = idx / (400 * 80);
    const float* cb = c + (size_t)b * 80 * 400 + f;
    const float* wr = w + o * 80;
    float acc = 0.f;
    #pragma unroll 8
    for (int j = 0; j < 80; ++j) acc += wr[j] * cb[(size_t)j * 400];
    c1[idx] = acc;
}

// repeat x10 + 21-tap smooth. src is piecewise-constant over runs of 10, so the
// 21 taps only touch src[u-1], src[u], src[u+1] with partial-sum weights by r=t%10.
__global__ void k_up0(const float* __restrict__ c1, const float* __restrict__ w,
                      float* __restrict__ c2) {
    int idx = blockIdx.x * blockDim.x + threadIdx.x;
    if (idx >= BATCH * 80 * 4000) return;
    int t = idx % 4000;
    int ch = idx / 4000;
    int u = t / 10, r = t - u * 10;
    float w0 = 0.f, w1 = 0.f, w2 = 0.f;
    #pragma unroll
    for (int j = 0; j < 21; ++j) {
        float wj = w[j];
        int a = r - 10 + j;          // in [-10, 19]
        if (a < 0) w0 += wj;
        else if (a < 10) w1 += wj;
        else w2 += wj;
    }
    const float* src = c1 + (size_t)ch * 400;
    float s0 = (u >= 1) ? src[u - 1] : 0.f;
    float s1 = src[u];
    float s2 = (u + 1 < 400) ? src[u + 1] : 0.f;
    c2[idx] = w0 * s0 + w1 * s1 + w2 * s2;
}

// repeat x8 + 17-tap smooth, output bf16 t-major [b][t][96] (ch 80..95 zeroed pad).
// Same piecewise-constant decomposition: out[8u+r] = W0(r)*src[u-1]+W1(r)*src[u]+W2(r)*src[u+1].
// Per block: stage the 10 needed src values for all 80 channels in LDS (coalesced),
// build the 8x3 weight table, then 3 LDS reads + 3 FMA per output.
__global__ __launch_bounds__(256) void k_up1b(const float* __restrict__ c2,
                                              const float* __restrict__ w,
                                              unsigned short* __restrict__ cupb) {
    __shared__ float S[80][13];  // [ch][u - (u0-1)], stride 13 -> conflict-free
    __shared__ float W[8][4];    // [r][k]
    const int b = blockIdx.y, t0 = blockIdx.x * 64;
    const int tid = threadIdx.x;
    const int u0 = t0 >> 3;  // t0 multiple of 64 -> u0 multiple of 8

    for (int i = tid; i < 800; i += 256) {
        int ch = i / 10, uu = i % 10;
        int u = u0 - 1 + uu;
        float v = 0.f;
        if (u >= 0 && u < 4000) v = c2[((size_t)b * 80 + ch) * 4000 + u];
        S[ch][uu] = v;
    }
    if (tid < 24) {
        int r = tid / 3, k = tid % 3;
        // taps j with floor((r-8+j)/8) == k-1:
        // k=0: j in [0, 7-r]; k=1: j in [8-r, 15-r]; k=2: j in [16-r, 16]
        int jlo = (k == 0) ? 0 : (k == 1 ? 8 - r : 16 - r);
        int jhi = (k == 0) ? 7 - r : (k == 1 ? 15 - r : 16);
        float a = 0.f;
        for (int j = jlo; j <= jhi; ++j) a += w[j];
        W[r][k] = a;
    }
    __syncthreads();

    unsigned short* ob = cupb + ((size_t)b * T_TOTAL + t0) * 96;
    for (int i = tid; i < 64 * 96; i += 256) {
        int ch = i % 96;
        int tl = i / 96;
        float acc = 0.f;
        if (ch < 80) {
            int r = tl & 7, ub = tl >> 3;
            acc = W[r][0] * S[ch][ub] + W[r][1] * S[ch][ub + 1] + W[r][2] * S[ch][ub + 2];
        }
        ob[i] = f2b(acc);
    }
}

// ---------------- first 1x1 conv (MFMA): h0[b][t][64] = first_w @ x + b -------
__global__ __launch_bounds__(256, 4) void k_first(
    const float* __restrict__ x, const unsigned short* __restrict__ fwp,
    const float* __restrict__ fb, float* __restrict__ h0) {
    __shared__ unsigned short Xf[64 * 264];  // [t][k], row stride 264 bf16
    const int b = blockIdx.y, t0 = blockIdx.x * TT, tid = threadIdx.x;
    const int lane = tid & 63;
    const int wv = __builtin_amdgcn_readfirstlane(tid >> 6);
    const int l15 = lane & 15, q = lane >> 4;

    // stage + transpose: x is [b][256 ch][T] fp32 -> Xf[t][ch] bf16
    for (int i = tid; i < 2048; i += 256) {
        int tb = i >> 8, ch = i & 255;
        const float* xr = x + ((size_t)b * 256 + ch) * T_TOTAL + t0 + tb * 8;
        float4 u0 = *(const float4*)xr;
        float4 u1 = *(const float4*)(xr + 4);
        int base = (tb * 8) * 264 + ch;
        Xf[base + 0 * 264] = f2b(u0.x);
        Xf[base + 1 * 264] = f2b(u0.y);
        Xf[base + 2 * 264] = f2b(u0.z);
        Xf[base + 3 * 264] = f2b(u0.w);
        Xf[base + 4 * 264] = f2b(u1.x);
        Xf[base + 5 * 264] = f2b(u1.y);
        Xf[base + 6 * 264] = f2b(u1.z);
        Xf[base + 7 * 264] = f2b(u1.w);
    }
    __syncthreads();

    f32x4 acc[4] = {};
    const unsigned short* wr = fwp + (size_t)(16 * wv + l15) * 256;
    #pragma unroll
    for (int ks = 0; ks < 8; ++ks) {
        bf16x8 aA = ld_bf8(wr + ks * 32 + q * 8);
        #pragma unroll
        for (int tt = 0; tt < 4; ++tt) {
            bf16x8 bb = ld_bf8(&Xf[(tt * 16 + l15) * 264 + ks * 32 + q * 8]);
            acc[tt] = __builtin_amdgcn_mfma_f32_16x16x32_bf16(aA, bb, acc[tt], 0, 0, 0);
        }
    }
    const float4 fbv = *(const float4*)&fb[16 * wv + 4 * q];
    float* hob = h0 + (size_t)b * T_TOTAL * 64;
    #pragma unroll
    for (int tt = 0; tt < 4; ++tt) {
        size_t base = (size_t)(t0 + tt * 16 + l15) * 64 + 16 * wv + 4 * q;
        float4 ho;
        ho.x = acc[tt][0] + fbv.x;
        ho.y = acc[tt][1] + fbv.y;
        ho.z = acc[tt][2] + fbv.z;
        ho.w = acc[tt][3] + fbv.w;
        *(float4*)(hob + base) = ho;
    }
}

// ---------------- fused WaveNet layer (MFMA) ----------------
__global__ __launch_bounds__(256, 4) void k_layer(
    const float* __restrict__ h_in, float* __restrict__ h_out,
    float* __restrict__ skips, const unsigned short* __restrict__ cupb,
    const unsigned short* __restrict__ wgp, const unsigned short* __restrict__ wzp,
    const float* __restrict__ cb_l, const float* __restrict__ ob_l,
    const float* __restrict__ sb_l, int d, int first) {
    __shared__ unsigned short Xl[64 * 224];  // [t][k], k: 0..63 h(t-d), 64..127 h(t), 128..223 cond(+pad)
    __shared__ unsigned short zs[64 * 72];   // [t][o] z tile, row stride 72
    const int b = blockIdx.y, t0 = blockIdx.x * TT, tid = threadIdx.x;
    const int lane = tid & 63;
    const int wv = __builtin_amdgcn_readfirstlane(tid >> 6);
    const int l15 = lane & 15, q = lane >> 4;

    const float* hb = h_in + (size_t)b * T_TOTAL * 64;
    // stage taps (fp32 -> bf16)
    for (int i = tid; i < 512; i += 256) {
        int t = i >> 3, cb8 = (i & 7) << 3;
        const float4* p1 = (const float4*)(hb + (size_t)(t0 + t) * 64 + cb8);
        float4 u0 = p1[0], u1 = p1[1];
        uint4v v1;
        v1.x = f2b2(u0.x, u0.y); v1.y = f2b2(u0.z, u0.w);
        v1.z = f2b2(u1.x, u1.y); v1.w = f2b2(u1.z, u1.w);
        *(uint4v*)&Xl[t * 224 + 64 + cb8] = v1;
        int td = t0 + t - d;
        uint4v v0 = {0u, 0u, 0u, 0u};
        if (td >= 0) {
            const float4* p0 = (const float4*)(hb + (size_t)td * 64 + cb8);
            float4 w0 = p0[0], w1 = p0[1];
            v0.x = f2b2(w0.x, w0.y); v0.y = f2b2(w0.z, w0.w);
            v0.z = f2b2(w1.x, w1.y); v0.w = f2b2(w1.z, w1.w);
        }
        *(uint4v*)&Xl[t * 224 + cb8] = v0;
    }
    // stage conditioning (already bf16, includes zero pad ch 80..95)
    const unsigned short* cbb = cupb + (size_t)b * T_TOTAL * 96;
    for (int i = tid; i < 768; i += 256) {
        int t = i / 12, j = (i % 12) << 3;
        *(uint4v*)&Xl[t * 224 + 128 + j] = *(const uint4v*)&cbb[(size_t)(t0 + t) * 96 + j];
    }
    __syncthreads();

    // gate GEMM: wave wv owns rows {16wv..+15} (a) and {64+16wv..+15} (g), all 4 t-tiles
    f32x4 accA[4] = {}, accG[4] = {};
    const unsigned short* wrow_a = wgp + (size_t)(16 * wv + l15) * 224;
    const unsigned short* wrow_g = wgp + (size_t)(64 + 16 * wv + l15) * 224;
    #pragma unroll
    for (int ks = 0; ks < 7; ++ks) {
        bf16x8 aA = ld_bf8(wrow_a + ks * 32 + q * 8);
        bf16x8 aG = ld_bf8(wrow_g + ks * 32 + q * 8);
        #pragma unroll
        for (int tt = 0; tt < 4; ++tt) {
            bf16x8 bb = ld_bf8(&Xl[(tt * 16 + l15) * 224 + ks * 32 + q * 8]);
            accA[tt] = __builtin_amdgcn_mfma_f32_16x16x32_bf16(aA, bb, accA[tt], 0, 0, 0);
            accG[tt] = __builtin_amdgcn_mfma_f32_16x16x32_bf16(aG, bb, accG[tt], 0, 0, 0);
        }
    }
    // activation -> z tile in LDS
    const float4 cbA = *(const float4*)&cb_l[16 * wv + 4 * q];
    const float4 cbG = *(const float4*)&cb_l[64 + 16 * wv + 4 * q];
    #pragma unroll
    for (int tt = 0; tt < 4; ++tt) {
        int t = tt * 16 + l15;
        float z0 = fast_tanh(accA[tt][0] + cbA.x) * fast_sigmoid(accG[tt][0] + cbG.x);
        float z1 = fast_tanh(accA[tt][1] + cbA.y) * fast_sigmoid(accG[tt][1] + cbG.y);
        float z2 = fast_tanh(accA[tt][2] + cbA.z) * fast_sigmoid(accG[tt][2] + cbG.z);
        float z3 = fast_tanh(accA[tt][3] + cbA.w) * fast_sigmoid(accG[tt][3] + cbG.w);
        uint2v zv;
        zv.x = f2b2(z0, z1);
        zv.y = f2b2(z2, z3);
        *(uint2v*)&zs[t * 72 + 16 * wv + 4 * q] = zv;
    }
    __syncthreads();

    // z GEMM: skip rows 16wv.., out rows 64+16wv..
    f32x4 accS[4] = {}, accO[4] = {};
    const unsigned short* zrow_s = wzp + (size_t)(16 * wv + l15) * 64;
    const unsigned short* zrow_o = wzp + (size_t)(64 + 16 * wv + l15) * 64;
    #pragma unroll
    for (int ks = 0; ks < 2; ++ks) {
        bf16x8 aS = ld_bf8(zrow_s + ks * 32 + q * 8);
        bf16x8 aO = ld_bf8(zrow_o + ks * 32 + q * 8);
        #pragma unroll
        for (int tt = 0; tt < 4; ++tt) {
            bf16x8 bb = ld_bf8(&zs[(tt * 16 + l15) * 72 + ks * 32 + q * 8]);
            accS[tt] = __builtin_amdgcn_mfma_f32_16x16x32_bf16(aS, bb, accS[tt], 0, 0, 0);
            accO[tt] = __builtin_amdgcn_mfma_f32_16x16x32_bf16(aO, bb, accO[tt], 0, 0, 0);
        }
    }
    const float4 sbv = *(const float4*)&sb_l[16 * wv + 4 * q];
    const float4 obv = *(const float4*)&ob_l[16 * wv + 4 * q];
    float* hob = h_out + (size_t)b * T_TOTAL * 64;
    float* skb = skips + (size_t)b * T_TOTAL * 64;
    #pragma unroll
    for (int tt = 0; tt < 4; ++tt) {
        size_t base = (size_t)(t0 + tt * 16 + l15) * 64 + 16 * wv + 4 * q;
        float4 hi = *(const float4*)(hb + base);
        float4 ho;
        ho.x = hi.x + accO[tt][0] + obv.x;
        ho.y = hi.y + accO[tt][1] + obv.y;
        ho.z = hi.z + accO[tt][2] + obv.z;
        ho.w = hi.w + accO[tt][3] + obv.w;
        *(float4*)(hob + base) = ho;
        float4 sv;
        if (first) {
            sv.x = accS[tt][0] + sbv.x;
            sv.y = accS[tt][1] + sbv.y;
            sv.z = accS[tt][2] + sbv.z;
            sv.w = accS[tt][3] + sbv.w;
        } else {
            float4 sp = *(const float4*)(skb + base);
            sv.x = sp.x + accS[tt][0] + sbv.x;
            sv.y = sp.y + accS[tt][1] + sbv.y;
            sv.z = sp.z + accS[tt][2] + sbv.z;
            sv.w = sp.w + accS[tt][3] + sbv.w;
        }
        *(float4*)(skb + base) = sv;
    }
}

// ---------------- last layers (MFMA): relu -> 1x1 -> relu -> 1x1 -------------
__global__ __launch_bounds__(256) void k_last(
    const float* __restrict__ skips, const unsigned short* __restrict__ l1p,
    const float* __restrict__ b1, const unsigned short* __restrict__ l2p,
    const float* __restrict__ b2, float* __restrict__ out) {
    __shared__ unsigned short sp[64 * 72];
    __shared__ unsigned short o2s[64 * 72];
    const int b = blockIdx.y, t0 = blockIdx.x * TT, tid = threadIdx.x;
    const int lane = tid & 63;
    const int wv = __builtin_amdgcn_readfirstlane(tid >> 6);
    const int l15 = lane & 15, q = lane >> 4;

    const float* skb = skips + (size_t)b * T_TOTAL * 64;
    for (int i = tid; i < 512; i += 256) {
        int t = i >> 3, cb8 = (i & 7) << 3;
        const float4* p = (const float4*)(skb + (size_t)(t0 + t) * 64 + cb8);
        float4 u0 = p[0], u1 = p[1];
        uint4v v;
        v.x = f2b2(fmaxf(u0.x, 0.f), fmaxf(u0.y, 0.f));
        v.y = f2b2(fmaxf(u0.z, 0.f), fmaxf(u0.w, 0.f));
        v.z = f2b2(fmaxf(u1.x, 0.f), fmaxf(u1.y, 0.f));
        v.w = f2b2(fmaxf(u1.z, 0.f), fmaxf(u1.w, 0.f));
        *(uint4v*)&sp[t * 72 + cb8] = v;
    }
    __syncthreads();

    f32x4 a1[4] = {};
    const unsigned short* w1r = l1p + (size_t)(16 * wv + l15) * 64;
    #pragma unroll
    for (int ks = 0; ks < 2; ++ks) {
        bf16x8 aA = ld_bf8(w1r + ks * 32 + q * 8);
        #pragma unroll
        for (int tt = 0; tt < 4; ++tt) {
            bf16x8 bb = ld_bf8(&sp[(tt * 16 + l15) * 72 + ks * 32 + q * 8]);
            a1[tt] = __builtin_amdgcn_mfma_f32_16x16x32_bf16(aA, bb, a1[tt], 0, 0, 0);
        }
    }
    const float4 b1v = *(const float4*)&b1[16 * wv + 4 * q];
    #pragma unroll
    for (int tt = 0; tt < 4; ++tt) {
        int t = tt * 16 + l15;
        float z0 = fmaxf(a1[tt][0] + b1v.x, 0.f);
        float z1 = fmaxf(a1[tt][1] + b1v.y, 0.f);
        float z2 = fmaxf(a1[tt][2] + b1v.z, 0.f);
        float z3 = fmaxf(a1[tt][3] + b1v.w, 0.f);
        uint2v zv;
        zv.x = f2b2(z0, z1);
        zv.y = f2b2(z2, z3);
        *(uint2v*)&o2s[t * 72 + 16 * wv + 4 * q] = zv;
    }
    __syncthreads();

    f32x4 a2[4][4] = {};  // [j][tt]; wave wv covers output rows 64*wv .. 64*wv+63
    #pragma unroll
    for (int ks = 0; ks < 2; ++ks) {
        bf16x8 aw[4];
        #pragma unroll
        for (int j = 0; j < 4; ++j)
            aw[j] = ld_bf8(l2p + (size_t)(64 * wv + 16 * j + l15) * 64 + ks * 32 + q * 8);
        #pragma unroll
        for (int tt = 0; tt < 4; ++tt) {
            bf16x8 bb = ld_bf8(&o2s[(tt * 16 + l15) * 72 + ks * 32 + q * 8]);
            #pragma unroll
            for (int j = 0; j < 4; ++j)
                a2[j][tt] = __builtin_amdgcn_mfma_f32_16x16x32_bf16(aw[j], bb, a2[j][tt], 0, 0, 0);
        }
    }
    float* ob = out + (size_t)b * 256 * T_TOTAL;
    #pragma unroll
    for (int j = 0; j < 4; ++j) {
        int o0 = 64 * wv + 16 * j + 4 * q;
        float4 b2v = *(const float4*)&b2[o0];
        #pragma unroll
        for (int tt = 0; tt < 4; ++tt) {
            int t = t0 + tt * 16 + l15;
            ob[(size_t)(o0 + 0) * T_TOTAL + t] = a2[j][tt][0] + b2v.x;
            ob[(size_t)(o0 + 1) * T_TOTAL + t] = a2[j][tt][1] + b2v.y;
            ob[(size_t)(o0 + 2) * T_TOTAL + t] = a2[j][tt][2] + b2v.z;
            ob[(size_t)(o0 + 3) * T_TOTAL + t] = a2[j][tt][3] + b2v.w;
        }
    }
}

extern "C" void kernel_launch(void* const* d_in, const int* in_sizes, int n_in,
                              void* d_out, int out_size, void* d_ws, size_t ws_size,
                              hipStream_t stream) {
    const float* x         = (const float*)d_in[0];
    const float* c         = (const float*)d_in[1];
    const float* first_w   = (const float*)d_in[2];
    const float* first_b   = (const float*)d_in[3];
    const float* conv_w    = (const float*)d_in[4];
    const float* conv_b    = (const float*)d_in[5];
    const float* cond_w    = (const float*)d_in[6];
    const float* out_w     = (const float*)d_in[7];
    const float* out_b     = (const float*)d_in[8];
    const float* skip_w    = (const float*)d_in[9];
    const float* skip_b    = (const float*)d_in[10];
    const float* last1_w   = (const float*)d_in[11];
    const float* last1_b   = (const float*)d_in[12];
    const float* last2_w   = (const float*)d_in[13];
    const float* last2_b   = (const float*)d_in[14];
    const float* conv_in_w = (const float*)d_in[15];
    const float* up_w0     = (const float*)d_in[16];
    const float* up_w1     = (const float*)d_in[17];

    unsigned char* base = (unsigned char*)d_ws;
    float* c1            = (float*)(base + 0);            //   512,000 B
    float* c2            = (float*)(base + 512000);       // 5,120,000 B
    unsigned short* cupb = (unsigned short*)(base + 5632000);    // 24,576,000 B
    float* hA            = (float*)(base + 30208000);     // 32,768,000 B
    float* hB            = (float*)(base + 62976000);     // 32,768,000 B
    float* skips         = (float*)(base + 95744000);     // 32,768,000 B
    unsigned short* wgp  = (unsigned short*)(base + 128512000);  // 1,720,320 B
    unsigned short* wzp  = (unsigned short*)(base + 130232320);  //   491,520 B
    unsigned short* fwp  = (unsigned short*)(base + 130723840);  //    32,768 B
    unsigned short* l1p  = (unsigned short*)(base + 130756608);  //     8,192 B
    unsigned short* l2p  = (unsigned short*)(base + 130764800);  //    32,768 B

    k_pack<<<(1142784 + 255) / 256, 256, 0, stream>>>(
        conv_w, cond_w, skip_w, out_w, first_w, last1_w, last2_w,
        wgp, wzp, fwp, l1p, l2p);
    k_convin<<<(BATCH * 80 * 400 + 255) / 256, 256, 0, stream>>>(c, conv_in_w, c1);
    k_up0<<<(BATCH * 80 * 4000 + 255) / 256, 256, 0, stream>>>(c1, up_w0, c2);
    dim3 upg(T_TOTAL / 64, BATCH);
    k_up1b<<<upg, 256, 0, stream>>>(c2, up_w1, cupb);

    dim3 grid(T_TOTAL / TT, BATCH);
    k_first<<<grid, 256, 0, stream>>>(x, fwp, first_b, hA);

    float* hin = hA;
    float* hout = hB;
    for (int l = 0; l < 30; ++l) {
        int d = 1 << (l % 10);
        k_layer<<<grid, 256, 0, stream>>>(
            hin, hout, skips, cupb,
            wgp + (size_t)l * 128 * 224, wzp + (size_t)l * 128 * 64,
            conv_b + (size_t)l * 128, out_b + (size_t)l * 64, skip_b + (size_t)l * 64,
            d, l == 0 ? 1 : 0);
        float* tmp = hin; hin = hout; hout = tmp;
    }

    k_last<<<grid, 256, 0, stream>>>(skips, l1p, last1_b, l2p, last2_b, (float*)d_out);
}

// Round 2
// 1493.136 us; speedup vs baseline: 1.2692x; 1.0074x over previous
//
#include <hip/hip_runtime.h>
#include <math.h>

#define T_TOTAL 32000
#define BATCH 4
#define TT 64

typedef __bf16 bf16x8 __attribute__((ext_vector_type(8)));
typedef float f32x4 __attribute__((ext_vector_type(4)));
typedef unsigned int uint4v __attribute__((ext_vector_type(4)));
typedef unsigned int uint2v __attribute__((ext_vector_type(2)));

__device__ __forceinline__ unsigned short f2b(float f) {
    unsigned int u = __float_as_uint(f);
    u += 0x7FFFu + ((u >> 16) & 1u);
    return (unsigned short)(u >> 16);
}
__device__ __forceinline__ unsigned int f2b2(float lo, float hi) {
    return (unsigned int)f2b(lo) | ((unsigned int)f2b(hi) << 16);
}
__device__ __forceinline__ bf16x8 ld_bf8(const unsigned short* p) {
    return __builtin_bit_cast(bf16x8, *(const uint4v*)p);
}
__device__ __forceinline__ float fast_sigmoid(float x) {
    return __builtin_amdgcn_rcpf(1.0f + __expf(-x));
}
__device__ __forceinline__ float fast_tanh(float x) {
    return 1.0f - 2.0f * __builtin_amdgcn_rcpf(1.0f + __expf(2.0f * x));
}

// ---------------- weight packing (fp32 -> bf16, fused/padded layouts) ----------
// wgp[l][o(128)][k(224)]: k 0..63 = conv_w[..][k][0] (tap t-d), 64..127 = tap t,
//                         128..207 = cond_w, 208..223 = 0
// wzp[l][r(128)][k(64)]:  r 0..63 = skip_w rows, 64..127 = out_w rows
// sbs[64] = sum over layers of skip_b (only when do_sbs)
__global__ void k_pack(const float* __restrict__ conv_w, const float* __restrict__ cond_w,
                       const float* __restrict__ skip_w, const float* __restrict__ out_w,
                       const float* __restrict__ first_w, const float* __restrict__ last1_w,
                       const float* __restrict__ last2_w, const float* __restrict__ skip_b,
                       unsigned short* __restrict__ wgp, unsigned short* __restrict__ wzp,
                       unsigned short* __restrict__ fwp, unsigned short* __restrict__ l1p,
                       unsigned short* __restrict__ l2p, float* __restrict__ sbs, int do_sbs) {
    int i = blockIdx.x * blockDim.x + threadIdx.x;
    if (i < 860160) {  // wgp: 30*128*224
        int l = i / 28672, r = i % 28672;
        int o = r / 224, k = r % 224;
        float v;
        if (k < 64)       v = conv_w[(((size_t)l * 128 + o) * 64 + k) * 2 + 0];
        else if (k < 128) v = conv_w[(((size_t)l * 128 + o) * 64 + (k - 64)) * 2 + 1];
        else if (k < 208) v = cond_w[((size_t)l * 128 + o) * 80 + (k - 128)];
        else              v = 0.0f;
        wgp[i] = f2b(v);
        return;
    }
    i -= 860160;
    if (i < 245760) {  // wzp: 30*128*64
        int l = i / 8192, rr = (i % 8192) / 64, k = i % 64;
        float v = (rr < 64) ? skip_w[((size_t)l * 64 + rr) * 64 + k]
                            : out_w[((size_t)l * 64 + (rr - 64)) * 64 + k];
        wzp[i] = f2b(v);
        return;
    }
    i -= 245760;
    if (i < 16384) { fwp[i] = f2b(first_w[i]); return; }   // 64*256
    i -= 16384;
    if (i < 4096) { l1p[i] = f2b(last1_w[i]); return; }    // 64*64
    i -= 4096;
    if (i < 16384) { l2p[i] = f2b(last2_w[i]); return; }   // 256*64
    i -= 16384;
    if (i < 64 && do_sbs) {
        float a = 0.f;
        for (int l = 0; l < 30; ++l) a += skip_b[l * 64 + i];
        sbs[i] = a;
    }
}

// ---------------- upsample network ----------------
__global__ void k_convin(const float* __restrict__ c, const float* __restrict__ w,
                         float* __restrict__ c1) {
    int idx = blockIdx.x * blockDim.x + threadIdx.x;
    if (idx >= BATCH * 80 * 400) return;
    int f = idx % 400;
    int o = (idx / 400) % 80;
    int b = idx / (400 * 80);
    const float* cb = c + (size_t)b * 80 * 400 + f;
    const float* wr = w + o * 80;
    float acc = 0.f;
    #pragma unroll 8
    for (int j = 0; j < 80; ++j) acc += wr[j] * cb[(size_t)j * 400];
    c1[idx] = acc;
}

// repeat x10 + 21-tap smooth via piecewise-constant decomposition (3 src values)
__global__ void k_up0(const float* __restrict__ c1, const float* __restrict__ w,
                      float* __restrict__ c2) {
    int idx = blockIdx.x * blockDim.x + threadIdx.x;
    if (idx >= BATCH * 80 * 4000) return;
    int t = idx % 4000;
    int ch = idx / 4000;
    int u = t / 10, r = t - u * 10;
    float w0 = 0.f, w1 = 0.f, w2 = 0.f;
    #pragma unroll
    for (int j = 0; j < 21; ++j) {
        float wj = w[j];
        int a = r - 10 + j;          // in [-10, 19]
        if (a < 0) w0 += wj;
        else if (a < 10) w1 += wj;
        else w2 += wj;
    }
    const float* src = c1 + (size_t)ch * 400;
    float s0 = (u >= 1) ? src[u - 1] : 0.f;
    float s1 = src[u];
    float s2 = (u + 1 < 400) ? src[u + 1] : 0.f;
    c2[idx] = w0 * s0 + w1 * s1 + w2 * s2;
}

// repeat x8 + 17-tap smooth, output bf16 t-major [b][t][96] (ch 80..95 zeroed pad).
__global__ __launch_bounds__(256) void k_up1b(const float* __restrict__ c2,
                                              const float* __restrict__ w,
                                              unsigned short* __restrict__ cupb) {
    __shared__ float S[80][13];
    __shared__ float W[8][4];
    const int b = blockIdx.y, t0 = blockIdx.x * 64;
    const int tid = threadIdx.x;
    const int u0 = t0 >> 3;

    for (int i = tid; i < 800; i += 256) {
        int ch = i / 10, uu = i % 10;
        int u = u0 - 1 + uu;
        float v = 0.f;
        if (u >= 0 && u < 4000) v = c2[((size_t)b * 80 + ch) * 4000 + u];
        S[ch][uu] = v;
    }
    if (tid < 24) {
        int r = tid / 3, k = tid % 3;
        int jlo = (k == 0) ? 0 : (k == 1 ? 8 - r : 16 - r);
        int jhi = (k == 0) ? 7 - r : (k == 1 ? 15 - r : 16);
        float a = 0.f;
        for (int j = jlo; j <= jhi; ++j) a += w[j];
        W[r][k] = a;
    }
    __syncthreads();

    unsigned short* ob = cupb + ((size_t)b * T_TOTAL + t0) * 96;
    for (int i = tid; i < 64 * 96; i += 256) {
        int ch = i % 96;
        int tl = i / 96;
        float acc = 0.f;
        if (ch < 80) {
            int r = tl & 7, ub = tl >> 3;
            acc = W[r][0] * S[ch][ub] + W[r][1] * S[ch][ub + 1] + W[r][2] * S[ch][ub + 2];
        }
        ob[i] = f2b(acc);
    }
}

// ---------------- first 1x1 conv (MFMA): h0[b][t][64] = first_w @ x + b -------
// Staging v2: 16-lane groups read 256 contiguous bytes along t (coalesced);
// Xf row stride 266 keeps both the column-writes and the MFMA b128 reads ~2-way.
#define XFS 266
__global__ __launch_bounds__(256, 4) void k_first(
    const float* __restrict__ x, const unsigned short* __restrict__ fwp,
    const float* __restrict__ fb, float* __restrict__ h0) {
    __shared__ unsigned short Xf[64 * XFS];
    const int b = blockIdx.y, t0 = blockIdx.x * TT, tid = threadIdx.x;
    const int lane = tid & 63;
    const int wv = __builtin_amdgcn_readfirstlane(tid >> 6);
    const int l15 = lane & 15, q = lane >> 4;

    // stage + transpose: x is [b][256 ch][T] fp32 -> Xf[t][ch] bf16
    for (int i = tid; i < 4096; i += 256) {
        int ch = i >> 4;            // 0..255
        int t4 = (i & 15) << 2;     // 0,4,...,60 ; 16 lanes cover one row contiguously
        const float* xr = x + ((size_t)b * 256 + ch) * T_TOTAL + t0 + t4;
        float4 u = *(const float4*)xr;
        int base = t4 * XFS + ch;
        Xf[base + 0 * XFS] = f2b(u.x);
        Xf[base + 1 * XFS] = f2b(u.y);
        Xf[base + 2 * XFS] = f2b(u.z);
        Xf[base + 3 * XFS] = f2b(u.w);
    }
    __syncthreads();

    f32x4 acc[4] = {};
    const unsigned short* wr = fwp + (size_t)(16 * wv + l15) * 256;
    #pragma unroll
    for (int ks = 0; ks < 8; ++ks) {
        bf16x8 aA = ld_bf8(wr + ks * 32 + q * 8);
        #pragma unroll
        for (int tt = 0; tt < 4; ++tt) {
            bf16x8 bb = ld_bf8(&Xf[(tt * 16 + l15) * XFS + ks * 32 + q * 8]);
            acc[tt] = __builtin_amdgcn_mfma_f32_16x16x32_bf16(aA, bb, acc[tt], 0, 0, 0);
        }
    }
    const float4 fbv = *(const float4*)&fb[16 * wv + 4 * q];
    float* hob = h0 + (size_t)b * T_TOTAL * 64;
    #pragma unroll
    for (int tt = 0; tt < 4; ++tt) {
        size_t base = (size_t)(t0 + tt * 16 + l15) * 64 + 16 * wv + 4 * q;
        float4 ho;
        ho.x = acc[tt][0] + fbv.x;
        ho.y = acc[tt][1] + fbv.y;
        ho.z = acc[tt][2] + fbv.z;
        ho.w = acc[tt][3] + fbv.w;
        *(float4*)(hob + base) = ho;
    }
}

// ---------------- fused WaveNet layer v2 (MFMA, no skip accumulation) ---------
// Writes z tile (bf16) to zb_l [b][t][64]; skip GEMM deferred to k_skips.
__global__ __launch_bounds__(256, 4) void k_layer(
    const float* __restrict__ h_in, float* __restrict__ h_out,
    unsigned short* __restrict__ zb_l, const unsigned short* __restrict__ cupb,
    const unsigned short* __restrict__ wgp_l, const unsigned short* __restrict__ wzp_l,
    const float* __restrict__ cb_l, const float* __restrict__ ob_l, int d) {
    __shared__ unsigned short Xl[64 * 224];
    __shared__ unsigned short zs[64 * 72];
    const int b = blockIdx.y, t0 = blockIdx.x * TT, tid = threadIdx.x;
    const int lane = tid & 63;
    const int wv = __builtin_amdgcn_readfirstlane(tid >> 6);
    const int l15 = lane & 15, q = lane >> 4;

    const float* hb = h_in + (size_t)b * T_TOTAL * 64;
    for (int i = tid; i < 512; i += 256) {
        int t = i >> 3, cb8 = (i & 7) << 3;
        const float4* p1 = (const float4*)(hb + (size_t)(t0 + t) * 64 + cb8);
        float4 u0 = p1[0], u1 = p1[1];
        uint4v v1;
        v1.x = f2b2(u0.x, u0.y); v1.y = f2b2(u0.z, u0.w);
        v1.z = f2b2(u1.x, u1.y); v1.w = f2b2(u1.z, u1.w);
        *(uint4v*)&Xl[t * 224 + 64 + cb8] = v1;
        int td = t0 + t - d;
        uint4v v0 = {0u, 0u, 0u, 0u};
        if (td >= 0) {
            const float4* p0 = (const float4*)(hb + (size_t)td * 64 + cb8);
            float4 w0 = p0[0], w1 = p0[1];
            v0.x = f2b2(w0.x, w0.y); v0.y = f2b2(w0.z, w0.w);
            v0.z = f2b2(w1.x, w1.y); v0.w = f2b2(w1.z, w1.w);
        }
        *(uint4v*)&Xl[t * 224 + cb8] = v0;
    }
    const unsigned short* cbb = cupb + (size_t)b * T_TOTAL * 96;
    for (int i = tid; i < 768; i += 256) {
        int t = i / 12, j = (i % 12) << 3;
        *(uint4v*)&Xl[t * 224 + 128 + j] = *(const uint4v*)&cbb[(size_t)(t0 + t) * 96 + j];
    }
    __syncthreads();

    f32x4 accA[4] = {}, accG[4] = {};
    const unsigned short* wrow_a = wgp_l + (size_t)(16 * wv + l15) * 224;
    const unsigned short* wrow_g = wgp_l + (size_t)(64 + 16 * wv + l15) * 224;
    #pragma unroll
    for (int ks = 0; ks < 7; ++ks) {
        bf16x8 aA = ld_bf8(wrow_a + ks * 32 + q * 8);
        bf16x8 aG = ld_bf8(wrow_g + ks * 32 + q * 8);
        #pragma unroll
        for (int tt = 0; tt < 4; ++tt) {
            bf16x8 bb = ld_bf8(&Xl[(tt * 16 + l15) * 224 + ks * 32 + q * 8]);
            accA[tt] = __builtin_amdgcn_mfma_f32_16x16x32_bf16(aA, bb, accA[tt], 0, 0, 0);
            accG[tt] = __builtin_amdgcn_mfma_f32_16x16x32_bf16(aG, bb, accG[tt], 0, 0, 0);
        }
    }
    const float4 cbA = *(const float4*)&cb_l[16 * wv + 4 * q];
    const float4 cbG = *(const float4*)&cb_l[64 + 16 * wv + 4 * q];
    #pragma unroll
    for (int tt = 0; tt < 4; ++tt) {
        int t = tt * 16 + l15;
        float z0 = fast_tanh(accA[tt][0] + cbA.x) * fast_sigmoid(accG[tt][0] + cbG.x);
        float z1 = fast_tanh(accA[tt][1] + cbA.y) * fast_sigmoid(accG[tt][1] + cbG.y);
        float z2 = fast_tanh(accA[tt][2] + cbA.z) * fast_sigmoid(accG[tt][2] + cbG.z);
        float z3 = fast_tanh(accA[tt][3] + cbA.w) * fast_sigmoid(accG[tt][3] + cbG.w);
        uint2v zv;
        zv.x = f2b2(z0, z1);
        zv.y = f2b2(z2, z3);
        *(uint2v*)&zs[t * 72 + 16 * wv + 4 * q] = zv;
    }
    __syncthreads();

    // write z tile to global (coalesced, 16B lanes); overlaps the out-GEMM below
    unsigned short* zg = zb_l + ((size_t)b * T_TOTAL + t0) * 64;
    #pragma unroll
    for (int it = 0; it < 2; ++it) {
        int i = tid + it * 256;
        int t = i >> 3, c8 = (i & 7) << 3;
        *(uint4v*)&zg[t * 64 + c8] = *(const uint4v*)&zs[t * 72 + c8];
    }

    // out GEMM only (h residual); skip GEMM deferred
    f32x4 accO[4] = {};
    const unsigned short* zrow_o = wzp_l + (size_t)(64 + 16 * wv + l15) * 64;
    #pragma unroll
    for (int ks = 0; ks < 2; ++ks) {
        bf16x8 aO = ld_bf8(zrow_o + ks * 32 + q * 8);
        #pragma unroll
        for (int tt = 0; tt < 4; ++tt) {
            bf16x8 bb = ld_bf8(&zs[(tt * 16 + l15) * 72 + ks * 32 + q * 8]);
            accO[tt] = __builtin_amdgcn_mfma_f32_16x16x32_bf16(aO, bb, accO[tt], 0, 0, 0);
        }
    }
    const float4 obv = *(const float4*)&ob_l[16 * wv + 4 * q];
    float* hob = h_out + (size_t)b * T_TOTAL * 64;
    #pragma unroll
    for (int tt = 0; tt < 4; ++tt) {
        size_t base = (size_t)(t0 + tt * 16 + l15) * 64 + 16 * wv + 4 * q;
        float4 hi = *(const float4*)(hb + base);
        float4 ho;
        ho.x = hi.x + accO[tt][0] + obv.x;
        ho.y = hi.y + accO[tt][1] + obv.y;
        ho.z = hi.z + accO[tt][2] + obv.z;
        ho.w = hi.w + accO[tt][3] + obv.w;
        *(float4*)(hob + base) = ho;
    }
}

// ---------------- fallback full layer (with fp32 skip accumulation) ----------
__global__ __launch_bounds__(256, 4) void k_layer_f(
    const float* __restrict__ h_in, float* __restrict__ h_out,
    float* __restrict__ skips, const unsigned short* __restrict__ cupb,
    const unsigned short* __restrict__ wgp, const unsigned short* __restrict__ wzp,
    const float* __restrict__ cb_l, const float* __restrict__ ob_l,
    const float* __restrict__ sb_l, int d, int first) {
    __shared__ unsigned short Xl[64 * 224];
    __shared__ unsigned short zs[64 * 72];
    const int b = blockIdx.y, t0 = blockIdx.x * TT, tid = threadIdx.x;
    const int lane = tid & 63;
    const int wv = __builtin_amdgcn_readfirstlane(tid >> 6);
    const int l15 = lane & 15, q = lane >> 4;

    const float* hb = h_in + (size_t)b * T_TOTAL * 64;
    for (int i = tid; i < 512; i += 256) {
        int t = i >> 3, cb8 = (i & 7) << 3;
        const float4* p1 = (const float4*)(hb + (size_t)(t0 + t) * 64 + cb8);
        float4 u0 = p1[0], u1 = p1[1];
        uint4v v1;
        v1.x = f2b2(u0.x, u0.y); v1.y = f2b2(u0.z, u0.w);
        v1.z = f2b2(u1.x, u1.y); v1.w = f2b2(u1.z, u1.w);
        *(uint4v*)&Xl[t * 224 + 64 + cb8] = v1;
        int td = t0 + t - d;
        uint4v v0 = {0u, 0u, 0u, 0u};
        if (td >= 0) {
            const float4* p0 = (const float4*)(hb + (size_t)td * 64 + cb8);
            float4 w0 = p0[0], w1 = p0[1];
            v0.x = f2b2(w0.x, w0.y); v0.y = f2b2(w0.z, w0.w);
            v0.z = f2b2(w1.x, w1.y); v0.w = f2b2(w1.z, w1.w);
        }
        *(uint4v*)&Xl[t * 224 + cb8] = v0;
    }
    const unsigned short* cbb = cupb + (size_t)b * T_TOTAL * 96;
    for (int i = tid; i < 768; i += 256) {
        int t = i / 12, j = (i % 12) << 3;
        *(uint4v*)&Xl[t * 224 + 128 + j] = *(const uint4v*)&cbb[(size_t)(t0 + t) * 96 + j];
    }
    __syncthreads();

    f32x4 accA[4] = {}, accG[4] = {};
    const unsigned short* wrow_a = wgp + (size_t)(16 * wv + l15) * 224;
    const unsigned short* wrow_g = wgp + (size_t)(64 + 16 * wv + l15) * 224;
    #pragma unroll
    for (int ks = 0; ks < 7; ++ks) {
        bf16x8 aA = ld_bf8(wrow_a + ks * 32 + q * 8);
        bf16x8 aG = ld_bf8(wrow_g + ks * 32 + q * 8);
        #pragma unroll
        for (int tt = 0; tt < 4; ++tt) {
            bf16x8 bb = ld_bf8(&Xl[(tt * 16 + l15) * 224 + ks * 32 + q * 8]);
            accA[tt] = __builtin_amdgcn_mfma_f32_16x16x32_bf16(aA, bb, accA[tt], 0, 0, 0);
            accG[tt] = __builtin_amdgcn_mfma_f32_16x16x32_bf16(aG, bb, accG[tt], 0, 0, 0);
        }
    }
    const float4 cbA = *(const float4*)&cb_l[16 * wv + 4 * q];
    const float4 cbG = *(const float4*)&cb_l[64 + 16 * wv + 4 * q];
    #pragma unroll
    for (int tt = 0; tt < 4; ++tt) {
        int t = tt * 16 + l15;
        float z0 = fast_tanh(accA[tt][0] + cbA.x) * fast_sigmoid(accG[tt][0] + cbG.x);
        float z1 = fast_tanh(accA[tt][1] + cbA.y) * fast_sigmoid(accG[tt][1] + cbG.y);
        float z2 = fast_tanh(accA[tt][2] + cbA.z) * fast_sigmoid(accG[tt][2] + cbG.z);
        float z3 = fast_tanh(accA[tt][3] + cbA.w) * fast_sigmoid(accG[tt][3] + cbG.w);
        uint2v zv;
        zv.x = f2b2(z0, z1);
        zv.y = f2b2(z2, z3);
        *(uint2v*)&zs[t * 72 + 16 * wv + 4 * q] = zv;
    }
    __syncthreads();

    f32x4 accS[4] = {}, accO[4] = {};
    const unsigned short* zrow_s = wzp + (size_t)(16 * wv + l15) * 64;
    const unsigned short* zrow_o = wzp + (size_t)(64 + 16 * wv + l15) * 64;
    #pragma unroll
    for (int ks = 0; ks < 2; ++ks) {
        bf16x8 aS = ld_bf8(zrow_s + ks * 32 + q * 8);
        bf16x8 aO = ld_bf8(zrow_o + ks * 32 + q * 8);
        #pragma unroll
        for (int tt = 0; tt < 4; ++tt) {
            bf16x8 bb = ld_bf8(&zs[(tt * 16 + l15) * 72 + ks * 32 + q * 8]);
            accS[tt] = __builtin_amdgcn_mfma_f32_16x16x32_bf16(aS, bb, accS[tt], 0, 0, 0);
            accO[tt] = __builtin_amdgcn_mfma_f32_16x16x32_bf16(aO, bb, accO[tt], 0, 0, 0);
        }
    }
    const float4 sbv = *(const float4*)&sb_l[16 * wv + 4 * q];
    const float4 obv = *(const float4*)&ob_l[16 * wv + 4 * q];
    float* hob = h_out + (size_t)b * T_TOTAL * 64;
    float* skb = skips + (size_t)b * T_TOTAL * 64;
    #pragma unroll
    for (int tt = 0; tt < 4; ++tt) {
        size_t base = (size_t)(t0 + tt * 16 + l15) * 64 + 16 * wv + 4 * q;
        float4 hi = *(const float4*)(hb + base);
        float4 ho;
        ho.x = hi.x + accO[tt][0] + obv.x;
        ho.y = hi.y + accO[tt][1] + obv.y;
        ho.z = hi.z + accO[tt][2] + obv.z;
        ho.w = hi.w + accO[tt][3] + obv.w;
        *(float4*)(hob + base) = ho;
        float4 sv;
        if (first) {
            sv.x = accS[tt][0] + sbv.x;
            sv.y = accS[tt][1] + sbv.y;
            sv.z = accS[tt][2] + sbv.z;
            sv.w = accS[tt][3] + sbv.w;
        } else {
            float4 sp = *(const float4*)(skb + base);
            sv.x = sp.x + accS[tt][0] + sbv.x;
            sv.y = sp.y + accS[tt][1] + sbv.y;
            sv.z = sp.z + accS[tt][2] + sbv.z;
            sv.w = sp.w + accS[tt][3] + sbv.w;
        }
        *(float4*)(skb + base) = sv;
    }
}

// ---------------- deferred skip reduction + last layers (MFMA) ---------------
// skips = sum_l skip_w[l] @ z_l + sbs ; relu ; last1 ; relu ; last2 -> out
__global__ __launch_bounds__(256) void k_skips(
    const unsigned short* __restrict__ zbuf, const unsigned short* __restrict__ wzp,
    const float* __restrict__ sbs, const unsigned short* __restrict__ l1p,
    const float* __restrict__ b1, const unsigned short* __restrict__ l2p,
    const float* __restrict__ b2, float* __restrict__ out) {
    __shared__ unsigned short zt[64 * 72];
    __shared__ unsigned short o2s[64 * 72];
    const int b = blockIdx.y, t0 = blockIdx.x * TT, tid = threadIdx.x;
    const int lane = tid & 63;
    const int wv = __builtin_amdgcn_readfirstlane(tid >> 6);
    const int l15 = lane & 15, q = lane >> 4;

    const int st_t = tid >> 3, st_c = (tid & 7) << 3;       // first staging slot
    const int st_t2 = (tid + 256) >> 3, st_c2 = ((tid + 256) & 7) << 3;
    const unsigned short* zb = zbuf + ((size_t)b * T_TOTAL + t0) * 64;

    f32x4 acc[4] = {};
    for (int l = 0; l < 30; ++l) {
        const unsigned short* src = zb + (size_t)l * BATCH * T_TOTAL * 64;
        *(uint4v*)&zt[st_t * 72 + st_c] = *(const uint4v*)&src[st_t * 64 + st_c];
        *(uint4v*)&zt[st_t2 * 72 + st_c2] = *(const uint4v*)&src[st_t2 * 64 + st_c2];
        __syncthreads();
        const unsigned short* wr = wzp + (size_t)l * 8192 + (size_t)(16 * wv + l15) * 64;
        #pragma unroll
        for (int ks = 0; ks < 2; ++ks) {
            bf16x8 aS = ld_bf8(wr + ks * 32 + q * 8);
            #pragma unroll
            for (int tt = 0; tt < 4; ++tt) {
                bf16x8 bb = ld_bf8(&zt[(tt * 16 + l15) * 72 + ks * 32 + q * 8]);
                acc[tt] = __builtin_amdgcn_mfma_f32_16x16x32_bf16(aS, bb, acc[tt], 0, 0, 0);
            }
        }
        __syncthreads();
    }

    // relu(skips) -> zt (bf16), reuse as last1 input
    const float4 sbv = *(const float4*)&sbs[16 * wv + 4 * q];
    #pragma unroll
    for (int tt = 0; tt < 4; ++tt) {
        int t = tt * 16 + l15;
        float s0 = fmaxf(acc[tt][0] + sbv.x, 0.f);
        float s1 = fmaxf(acc[tt][1] + sbv.y, 0.f);
        float s2 = fmaxf(acc[tt][2] + sbv.z, 0.f);
        float s3 = fmaxf(acc[tt][3] + sbv.w, 0.f);
        uint2v zv;
        zv.x = f2b2(s0, s1);
        zv.y = f2b2(s2, s3);
        *(uint2v*)&zt[t * 72 + 16 * wv + 4 * q] = zv;
    }
    __syncthreads();

    f32x4 a1[4] = {};
    const unsigned short* w1r = l1p + (size_t)(16 * wv + l15) * 64;
    #pragma unroll
    for (int ks = 0; ks < 2; ++ks) {
        bf16x8 aA = ld_bf8(w1r + ks * 32 + q * 8);
        #pragma unroll
        for (int tt = 0; tt < 4; ++tt) {
            bf16x8 bb = ld_bf8(&zt[(tt * 16 + l15) * 72 + ks * 32 + q * 8]);
            a1[tt] = __builtin_amdgcn_mfma_f32_16x16x32_bf16(aA, bb, a1[tt], 0, 0, 0);
        }
    }
    const float4 b1v = *(const float4*)&b1[16 * wv + 4 * q];
    #pragma unroll
    for (int tt = 0; tt < 4; ++tt) {
        int t = tt * 16 + l15;
        float z0 = fmaxf(a1[tt][0] + b1v.x, 0.f);
        float z1 = fmaxf(a1[tt][1] + b1v.y, 0.f);
        float z2 = fmaxf(a1[tt][2] + b1v.z, 0.f);
        float z3 = fmaxf(a1[tt][3] + b1v.w, 0.f);
        uint2v zv;
        zv.x = f2b2(z0, z1);
        zv.y = f2b2(z2, z3);
        *(uint2v*)&o2s[t * 72 + 16 * wv + 4 * q] = zv;
    }
    __syncthreads();

    f32x4 a2[4][4] = {};
    #pragma unroll
    for (int ks = 0; ks < 2; ++ks) {
        bf16x8 aw[4];
        #pragma unroll
        for (int j = 0; j < 4; ++j)
            aw[j] = ld_bf8(l2p + (size_t)(64 * wv + 16 * j + l15) * 64 + ks * 32 + q * 8);
        #pragma unroll
        for (int tt = 0; tt < 4; ++tt) {
            bf16x8 bb = ld_bf8(&o2s[(tt * 16 + l15) * 72 + ks * 32 + q * 8]);
            #pragma unroll
            for (int j = 0; j < 4; ++j)
                a2[j][tt] = __builtin_amdgcn_mfma_f32_16x16x32_bf16(aw[j], bb, a2[j][tt], 0, 0, 0);
        }
    }
    float* ob = out + (size_t)b * 256 * T_TOTAL;
    #pragma unroll
    for (int j = 0; j < 4; ++j) {
        int o0 = 64 * wv + 16 * j + 4 * q;
        float4 b2v = *(const float4*)&b2[o0];
        #pragma unroll
        for (int tt = 0; tt < 4; ++tt) {
            int t = t0 + tt * 16 + l15;
            ob[(size_t)(o0 + 0) * T_TOTAL + t] = a2[j][tt][0] + b2v.x;
            ob[(size_t)(o0 + 1) * T_TOTAL + t] = a2[j][tt][1] + b2v.y;
            ob[(size_t)(o0 + 2) * T_TOTAL + t] = a2[j][tt][2] + b2v.z;
            ob[(size_t)(o0 + 3) * T_TOTAL + t] = a2[j][tt][3] + b2v.w;
        }
    }
}

// ---------------- fallback last layers -----------------
__global__ __launch_bounds__(256) void k_last(
    const float* __restrict__ skips, const unsigned short* __restrict__ l1p,
    const float* __restrict__ b1, const unsigned short* __restrict__ l2p,
    const float* __restrict__ b2, float* __restrict__ out) {
    __shared__ unsigned short sp[64 * 72];
    __shared__ unsigned short o2s[64 * 72];
    const int b = blockIdx.y, t0 = blockIdx.x * TT, tid = threadIdx.x;
    const int lane = tid & 63;
    const int wv = __builtin_amdgcn_readfirstlane(tid >> 6);
    const int l15 = lane & 15, q = lane >> 4;

    const float* skb = skips + (size_t)b * T_TOTAL * 64;
    for (int i = tid; i < 512; i += 256) {
        int t = i >> 3, cb8 = (i & 7) << 3;
        const float4* p = (const float4*)(skb + (size_t)(t0 + t) * 64 + cb8);
        float4 u0 = p[0], u1 = p[1];
        uint4v v;
        v.x = f2b2(fmaxf(u0.x, 0.f), fmaxf(u0.y, 0.f));
        v.y = f2b2(fmaxf(u0.z, 0.f), fmaxf(u0.w, 0.f));
        v.z = f2b2(fmaxf(u1.x, 0.f), fmaxf(u1.y, 0.f));
        v.w = f2b2(fmaxf(u1.z, 0.f), fmaxf(u1.w, 0.f));
        *(uint4v*)&sp[t * 72 + cb8] = v;
    }
    __syncthreads();

    f32x4 a1[4] = {};
    const unsigned short* w1r = l1p + (size_t)(16 * wv + l15) * 64;
    #pragma unroll
    for (int ks = 0; ks < 2; ++ks) {
        bf16x8 aA = ld_bf8(w1r + ks * 32 + q * 8);
        #pragma unroll
        for (int tt = 0; tt < 4; ++tt) {
            bf16x8 bb = ld_bf8(&sp[(tt * 16 + l15) * 72 + ks * 32 + q * 8]);
            a1[tt] = __builtin_amdgcn_mfma_f32_16x16x32_bf16(aA, bb, a1[tt], 0, 0, 0);
        }
    }
    const float4 b1v = *(const float4*)&b1[16 * wv + 4 * q];
    #pragma unroll
    for (int tt = 0; tt < 4; ++tt) {
        int t = tt * 16 + l15;
        float z0 = fmaxf(a1[tt][0] + b1v.x, 0.f);
        float z1 = fmaxf(a1[tt][1] + b1v.y, 0.f);
        float z2 = fmaxf(a1[tt][2] + b1v.z, 0.f);
        float z3 = fmaxf(a1[tt][3] + b1v.w, 0.f);
        uint2v zv;
        zv.x = f2b2(z0, z1);
        zv.y = f2b2(z2, z3);
        *(uint2v*)&o2s[t * 72 + 16 * wv + 4 * q] = zv;
    }
    __syncthreads();

    f32x4 a2[4][4] = {};
    #pragma unroll
    for (int ks = 0; ks < 2; ++ks) {
        bf16x8 aw[4];
        #pragma unroll
        for (int j = 0; j < 4; ++j)
            aw[j] = ld_bf8(l2p + (size_t)(64 * wv + 16 * j + l15) * 64 + ks * 32 + q * 8);
        #pragma unroll
        for (int tt = 0; tt < 4; ++tt) {
            bf16x8 bb = ld_bf8(&o2s[(tt * 16 + l15) * 72 + ks * 32 + q * 8]);
            #pragma unroll
            for (int j = 0; j < 4; ++j)
                a2[j][tt] = __builtin_amdgcn_mfma_f32_16x16x32_bf16(aw[j], bb, a2[j][tt], 0, 0, 0);
        }
    }
    float* ob = out + (size_t)b * 256 * T_TOTAL;
    #pragma unroll
    for (int j = 0; j < 4; ++j) {
        int o0 = 64 * wv + 16 * j + 4 * q;
        float4 b2v = *(const float4*)&b2[o0];
        #pragma unroll
        for (int tt = 0; tt < 4; ++tt) {
            int t = t0 + tt * 16 + l15;
            ob[(size_t)(o0 + 0) * T_TOTAL + t] = a2[j][tt][0] + b2v.x;
            ob[(size_t)(o0 + 1) * T_TOTAL + t] = a2[j][tt][1] + b2v.y;
            ob[(size_t)(o0 + 2) * T_TOTAL + t] = a2[j][tt][2] + b2v.z;
            ob[(size_t)(o0 + 3) * T_TOTAL + t] = a2[j][tt][3] + b2v.w;
        }
    }
}

extern "C" void kernel_launch(void* const* d_in, const int* in_sizes, int n_in,
                              void* d_out, int out_size, void* d_ws, size_t ws_size,
                              hipStream_t stream) {
    const float* x         = (const float*)d_in[0];
    const float* c         = (const float*)d_in[1];
    const float* first_w   = (const float*)d_in[2];
    const float* first_b   = (const float*)d_in[3];
    const float* conv_w    = (const float*)d_in[4];
    const float* conv_b    = (const float*)d_in[5];
    const float* cond_w    = (const float*)d_in[6];
    const float* out_w     = (const float*)d_in[7];
    const float* out_b     = (const float*)d_in[8];
    const float* skip_w    = (const float*)d_in[9];
    const float* skip_b    = (const float*)d_in[10];
    const float* last1_w   = (const float*)d_in[11];
    const float* last1_b   = (const float*)d_in[12];
    const float* last2_w   = (const float*)d_in[13];
    const float* last2_b   = (const float*)d_in[14];
    const float* conv_in_w = (const float*)d_in[15];
    const float* up_w0     = (const float*)d_in[16];
    const float* up_w1     = (const float*)d_in[17];

    unsigned char* base = (unsigned char*)d_ws;
    const size_t NEED_BIG = 589549824ull;  // new layout incl. 491.5 MB zbuf
    const bool big = ws_size >= NEED_BIG;

    dim3 grid(T_TOTAL / TT, BATCH);
    dim3 upg(T_TOTAL / 64, BATCH);

    if (big) {
        float* c1            = (float*)(base + 0);
        float* c2            = (float*)(base + 512000);
        unsigned short* cupb = (unsigned short*)(base + 5632000);
        float* hA            = (float*)(base + 30208000);
        float* hB            = (float*)(base + 62976000);
        unsigned short* wgp  = (unsigned short*)(base + 95744000);
        unsigned short* wzp  = (unsigned short*)(base + 97464320);
        unsigned short* fwp  = (unsigned short*)(base + 97955840);
        unsigned short* l1p  = (unsigned short*)(base + 97988608);
        unsigned short* l2p  = (unsigned short*)(base + 97996800);
        float* sbs           = (float*)(base + 98029568);
        unsigned short* zbuf = (unsigned short*)(base + 98029824);

        k_pack<<<(1142848 + 255) / 256, 256, 0, stream>>>(
            conv_w, cond_w, skip_w, out_w, first_w, last1_w, last2_w, skip_b,
            wgp, wzp, fwp, l1p, l2p, sbs, 1);
        k_convin<<<(BATCH * 80 * 400 + 255) / 256, 256, 0, stream>>>(c, conv_in_w, c1);
        k_up0<<<(BATCH * 80 * 4000 + 255) / 256, 256, 0, stream>>>(c1, up_w0, c2);
        k_up1b<<<upg, 256, 0, stream>>>(c2, up_w1, cupb);

        k_first<<<grid, 256, 0, stream>>>(x, fwp, first_b, hA);

        float* hin = hA;
        float* hout = hB;
        for (int l = 0; l < 30; ++l) {
            int d = 1 << (l % 10);
            k_layer<<<grid, 256, 0, stream>>>(
                hin, hout, zbuf + (size_t)l * BATCH * T_TOTAL * 64, cupb,
                wgp + (size_t)l * 128 * 224, wzp + (size_t)l * 128 * 64,
                conv_b + (size_t)l * 128, out_b + (size_t)l * 64, d);
            float* tmp = hin; hin = hout; hout = tmp;
        }

        k_skips<<<grid, 256, 0, stream>>>(zbuf, wzp, sbs, l1p, last1_b, l2p, last2_b,
                                          (float*)d_out);
    } else {
        float* c1            = (float*)(base + 0);
        float* c2            = (float*)(base + 512000);
        unsigned short* cupb = (unsigned short*)(base + 5632000);
        float* hA            = (float*)(base + 30208000);
        float* hB            = (float*)(base + 62976000);
        float* skips         = (float*)(base + 95744000);
        unsigned short* wgp  = (unsigned short*)(base + 128512000);
        unsigned short* wzp  = (unsigned short*)(base + 130232320);
        unsigned short* fwp  = (unsigned short*)(base + 130723840);
        unsigned short* l1p  = (unsigned short*)(base + 130756608);
        unsigned short* l2p  = (unsigned short*)(base + 130764800);

        k_pack<<<(1142848 + 255) / 256, 256, 0, stream>>>(
            conv_w, cond_w, skip_w, out_w, first_w, last1_w, last2_w, skip_b,
            wgp, wzp, fwp, l1p, l2p, (float*)base, 0);
        k_convin<<<(BATCH * 80 * 400 + 255) / 256, 256, 0, stream>>>(c, conv_in_w, c1);
        k_up0<<<(BATCH * 80 * 4000 + 255) / 256, 256, 0, stream>>>(c1, up_w0, c2);
        k_up1b<<<upg, 256, 0, stream>>>(c2, up_w1, cupb);

        k_first<<<grid, 256, 0, stream>>>(x, fwp, first_b, hA);

        float* hin = hA;
        float* hout = hB;
        for (int l = 0; l < 30; ++l) {
            int d = 1 << (l % 10);
            k_layer_f<<<grid, 256, 0, stream>>>(
                hin, hout, skips, cupb,
                wgp + (size_t)l * 128 * 224, wzp + (size_t)l * 128 * 64,
                conv_b + (size_t)l * 128, out_b + (size_t)l * 64, skip_b + (size_t)l * 64,
                d, l == 0 ? 1 : 0);
            float* tmp = hin; hin = hout; hout = tmp;
        }

        k_last<<<grid, 256, 0, stream>>>(skips, l1p, last1_b, l2p, last2_b, (float*)d_out);
    }
}